// Round 3
// baseline (593.967 us; speedup 1.0000x reference)
//
#include <hip/hip_runtime.h>
#include <hip/hip_bf16.h>
#include <stdint.h>

#define BB 32
#define NN 2048
#define HH 128
#define BN (BB*NN)

typedef short v8s __attribute__((ext_vector_type(8)));
typedef float v4f __attribute__((ext_vector_type(4)));

__device__ __forceinline__ unsigned short f2b(float f){
  union { float f; unsigned int i; } v; v.f = f;
  unsigned int x = v.i;
  unsigned int r = x + 0x7FFFu + ((x >> 16) & 1u);   // RNE f32 -> bf16
  return (unsigned short)(r >> 16);
}
__device__ __forceinline__ unsigned int pk2(float a, float b){
  return (unsigned int)f2b(a) | ((unsigned int)f2b(b) << 16);
}
__device__ __forceinline__ float sigm(float x){ return 1.0f / (1.0f + __expf(-x)); }

// ---------------- pre-swizzle B = [Wi;Wh] (f32) into bf16 MFMA fragment order
// Bsw[((kc*32+ct)*64 + lane)*8 + j] = bf16(Bcat[kc*32 + (lane>>4)*8 + j][ct*16 + (lane&15)])
__global__ void kswz(const float* __restrict__ Wi0, const float* __restrict__ Wh0,
                     const float* __restrict__ Wi1, const float* __restrict__ Wh1,
                     unsigned short* __restrict__ Bsw0, unsigned short* __restrict__ Bsw1){
  int bid = blockIdx.x;            // 0..511
  int layer = bid >> 8;
  int kc = (bid >> 5) & 7;
  int ct = bid & 31;
  int lane = threadIdx.x;          // 0..63
  const float* Wi = layer ? Wi1 : Wi0;
  const float* Wh = layer ? Wh1 : Wh0;
  unsigned short* dst = layer ? Bsw1 : Bsw0;
  int col = ct*16 + (lane & 15);
  int kbase = kc*32 + (lane >> 4)*8;
  size_t o = ((size_t)(kc*32 + ct)*64 + (size_t)lane)*8;
  #pragma unroll
  for (int j = 0; j < 8; j++){
    int k = kbase + j;
    dst[o + j] = f2b((k < 128) ? Wi[k*512 + col] : Wh[(k-128)*512 + col]);
  }
}

// ---------------- save exit/raise rows of old states ------------------------
__global__ void ksave(const float* __restrict__ c0, const float* __restrict__ h0,
                      const float* __restrict__ c1, const float* __restrict__ h1,
                      const int* __restrict__ exit_idx, const int* __restrict__ raise_idx,
                      float* __restrict__ saved){
  int b = blockIdx.x, which = blockIdx.y, c = threadIdx.x;   // c: 0..511
  int idx = which ? raise_idx[b] : exit_idx[b];
  size_t row = (size_t)b*NN + idx;
  const float* bufs[4] = {c0, h0, c1, h1};
  saved[((size_t)b*2 + which)*512 + c] = bufs[c >> 7][row*128 + (c & 127)];
}

// ---------------- restore saved rows into (new) states ----------------------
__global__ void krestore(float* c0, float* h0, float* c1, float* h1,
                         const int* __restrict__ exit_idx, const int* __restrict__ raise_idx,
                         const float* __restrict__ saved){
  int b = blockIdx.x, which = blockIdx.y, c = threadIdx.x;
  int idx = which ? raise_idx[b] : exit_idx[b];
  size_t row = (size_t)b*NN + idx;
  float* bufs[4] = {c0, h0, c1, h1};
  bufs[c >> 7][row*128 + (c & 127)] = saved[((size_t)b*2 + which)*512 + c];
}

// ---------------- done batches: output = old states + old ip ----------------
__global__ __launch_bounds__(128) void kearly(
    const float* __restrict__ c0, const float* __restrict__ h0,
    const float* __restrict__ c1, const float* __restrict__ h1,
    const float* __restrict__ ip,
    const int* __restrict__ step_limits, const int* __restrict__ cur_step,
    float* __restrict__ out){
  int b = blockIdx.y;
  if (cur_step[0] < step_limits[b]) return;   // not done -> kagg handles it
  size_t row = (size_t)b*NN + blockIdx.x;
  int tid = threadIdx.x, c = tid*4;
  const float* bufs[4] = {c0, h0, c1, h1};
  const float* s = bufs[c >> 7];
  size_t rb = row*128 + (c & 127);
  size_t obase = row*513;
  out[obase + c+0] = s[rb+0];
  out[obase + c+1] = s[rb+1];
  out[obase + c+2] = s[rb+2];
  out[obase + c+3] = s[rb+3];
  if (tid == 0) out[obase + 512] = ip[row];
}

// ---------------- fused GEMM (A=[Aa|Ab] f32 -> bf16, K=256) + LSTM, IN PLACE
__global__ __launch_bounds__(512) void klstm(
    const float* Aa, const float* Ab,
    const unsigned short* Bsw, const float* bias,
    float* c_io, float* h_io)
{
  int tid = threadIdx.x;
  int wid = tid >> 6, lane = tid & 63;
  int wm = wid >> 2, wn = wid & 3;
  int quad = lane >> 4, l16 = lane & 15;
  int rbase = blockIdx.x * 32 + wm * 16;
  int arow = rbase + l16;

  v4f acc[8] = {};
  const float* apA = Aa + (size_t)arow*128;
  const float* apB = Ab + (size_t)arow*128;

  #pragma unroll
  for (int kc = 0; kc < 8; kc++){
    const float* ap = ((kc < 4) ? (apA + kc*32) : (apB + (kc-4)*32)) + quad*8;
    float4 x0 = *(const float4*)(ap);
    float4 x1 = *(const float4*)(ap + 4);
    union { v8s v; unsigned int u[4]; } af;
    af.u[0] = pk2(x0.x, x0.y);
    af.u[1] = pk2(x0.z, x0.w);
    af.u[2] = pk2(x1.x, x1.y);
    af.u[3] = pk2(x1.z, x1.w);
    #pragma unroll
    for (int t = 0; t < 8; t++){
      int ct = (t>>1)*8 + wn*2 + (t&1);   // gate*8 col-tiles; this wave's 2 per gate
      v8s b = *(const v8s*)(Bsw + ((size_t)(kc*32 + ct)*64 + lane)*8);
      acc[t] = __builtin_amdgcn_mfma_f32_16x16x32_bf16(af.v, b, acc[t], 0, 0, 0);
    }
  }

  // in-place update: all A reads above must complete before epilogue writes
  __syncthreads();

  // acc[t][r]: row = rbase + quad*4 + r ; col = (t>>1)*128 + wn*32 + (t&1)*16 + l16
  #pragma unroll
  for (int ch = 0; ch < 2; ch++){
    int j = wn*32 + ch*16 + l16;          // 0..127 within a gate
    float bi = bias[      j];
    float bf_= bias[128 + j];
    float bg = bias[256 + j];
    float bo = bias[384 + j];
    #pragma unroll
    for (int r = 0; r < 4; r++){
      size_t row = (size_t)rbase + quad*4 + r;
      float iv = acc[0+ch][r] + bi;
      float fv = acc[2+ch][r] + bf_;
      float gv = acc[4+ch][r] + bg;
      float ov = acc[6+ch][r] + bo;
      float cold = c_io[row*128 + j];
      float cn = sigm(fv)*cold + sigm(iv)*tanhf(gv);
      float hn = sigm(ov)*tanhf(cn);
      c_io[row*128 + j] = cn;
      h_io[row*128 + j] = hn;
    }
  }
}

// ---------------- decisions: softmax(hs @ W) -> edge weights wr/wt/wf -------
__global__ __launch_bounds__(256) void kdec(
    const float* __restrict__ c0, const float* __restrict__ h0,
    const float* __restrict__ c1, const float* __restrict__ h1,
    const float* __restrict__ Wr, const float* __restrict__ br,
    const float* __restrict__ Wb, const float* __restrict__ bb,
    const float* __restrict__ ip,
    const int* __restrict__ exit_idx, const int* __restrict__ raise_idx,
    float* __restrict__ wbuf)
{
  int tid = threadIdx.x;
  int wid = tid >> 6, lane = tid & 63;
  int gid = blockIdx.x*4 + wid;          // node id
  int b = gid >> 11, n = gid & 2047;

  const float* bufs[4] = {c0, h0, c1, h1};
  const float* hb = bufs[lane >> 4] + (size_t)gid*128 + (lane & 15)*8;
  float4 hv0 = *(const float4*)hb;
  float4 hv1 = *(const float4*)(hb + 4);
  float hv[8] = {hv0.x, hv0.y, hv0.z, hv0.w, hv1.x, hv1.y, hv1.z, hv1.w};
  const float* wrp = Wr + lane*16;
  const float* wbp = Wb + lane*16;
  float r0=0.f, r1=0.f, q0=0.f, q1=0.f;
  #pragma unroll
  for (int j = 0; j < 8; j++){
    float h = hv[j];
    r0 += h * wrp[j*2];  r1 += h * wrp[j*2+1];
    q0 += h * wbp[j*2];  q1 += h * wbp[j*2+1];
  }
  #pragma unroll
  for (int off = 32; off > 0; off >>= 1){
    r0 += __shfl_xor(r0, off, 64);
    r1 += __shfl_xor(r1, off, 64);
    q0 += __shfl_xor(q0, off, 64);
    q1 += __shfl_xor(q1, off, 64);
  }
  if (lane == 0){
    r0 += br[0]; r1 += br[1];
    q0 += bb[0]; q1 += bb[1];
    float pr, pn;
    if (n == exit_idx[b] || n == raise_idx[b]){ pr = 0.f; pn = 1.f; }
    else {
      float m = fmaxf(r0, r1);
      float e0 = __expf(r0 - m), e1 = __expf(r1 - m);
      pr = e0 / (e0 + e1); pn = e1 / (e0 + e1);
    }
    float m2 = fmaxf(q0, q1);
    float f0 = __expf(q0 - m2), f1 = __expf(q1 - m2);
    float pt = f0 / (f0 + f1), pf = f1 / (f0 + f1);
    float ipv = ip[gid];
    wbuf[0*BN + gid] = pr * ipv;
    wbuf[1*BN + gid] = pn * pt * ipv;
    wbuf[2*BN + gid] = pn * pf * ipv;
  }
}

// ---------------- CSR build: count / scan / fill ----------------------------
__global__ void kcount(const int* __restrict__ ri, const int* __restrict__ ti,
                       const int* __restrict__ fi, int* __restrict__ counts){
  int gid = blockIdx.x*256 + threadIdx.x;
  int base = (gid >> 11) << 11;
  atomicAdd(&counts[base + ri[gid]], 1);
  atomicAdd(&counts[base + ti[gid]], 1);
  atomicAdd(&counts[base + fi[gid]], 1);
}

__global__ __launch_bounds__(256) void kscan(const int* __restrict__ counts,
                                             int* __restrict__ offsets){
  __shared__ int lds[256];
  int b = blockIdx.x, tid = threadIdx.x;
  const int* c = counts + b*NN;
  int* o = offsets + b*NN;
  int v[8]; int s = 0;
  #pragma unroll
  for (int i = 0; i < 8; i++){ v[i] = c[tid*8+i]; s += v[i]; }
  lds[tid] = s;
  __syncthreads();
  if (tid == 0){
    int run = 0;
    for (int t = 0; t < 256; t++){ int tmp = lds[t]; lds[t] = run; run += tmp; }
  }
  __syncthreads();
  int off = lds[tid];
  #pragma unroll
  for (int i = 0; i < 8; i++){ o[tid*8+i] = off; off += v[i]; }
}

__global__ void kfill(const int* __restrict__ ri, const int* __restrict__ ti,
                      const int* __restrict__ fi, const int* __restrict__ offsets,
                      int* __restrict__ cursor, unsigned short* __restrict__ edges){
  int gid = blockIdx.x*256 + threadIdx.x;
  int b = gid >> 11, n = gid & 2047;
  size_t ebase = (size_t)b*3*NN;
  int t0 = ri[gid]; int p0 = atomicAdd(&cursor[b*NN+t0], 1);
  edges[ebase + offsets[b*NN+t0] + p0] = (unsigned short)(n);
  int t1 = ti[gid]; int p1 = atomicAdd(&cursor[b*NN+t1], 1);
  edges[ebase + offsets[b*NN+t1] + p1] = (unsigned short)(n | (1<<11));
  int t2 = fi[gid]; int p2 = atomicAdd(&cursor[b*NN+t2], 1);
  edges[ebase + offsets[b*NN+t2] + p2] = (unsigned short)(n | (2<<11));
}

// ---------------- gather + normalize + output (not-done batches) ------------
__global__ __launch_bounds__(128) void kagg(
    const float* __restrict__ c0, const float* __restrict__ h0,
    const float* __restrict__ c1, const float* __restrict__ h1,
    const float* __restrict__ wbuf, const unsigned short* __restrict__ edges,
    const int* __restrict__ counts, const int* __restrict__ offsets,
    const int* __restrict__ step_limits, const int* __restrict__ cur_step,
    float* __restrict__ out)
{
  int gid = blockIdx.x;            // b*N + j
  int b = gid >> 11;
  if (cur_step[0] >= step_limits[b]) return;   // done -> kearly wrote it
  int tid = threadIdx.x;           // 0..127, channels tid*4..tid*4+3
  int cnt = counts[gid], off = offsets[gid];
  const unsigned short* eb = edges + (size_t)b*3*NN + off;
  const float* bufs[4] = {c0, h0, c1, h1};
  const float* sb = bufs[tid >> 5];
  int coff = (tid & 31)*4;
  float a0=0.f, a1=0.f, a2=0.f, a3=0.f, ipn=0.f;
  for (int e = 0; e < cnt; e++){
    int pk = eb[e];
    int n = pk & 2047, et = pk >> 11;
    float w = wbuf[et*BN + (b<<11) + n];
    ipn += w;
    float4 sv = *(const float4*)(sb + ((size_t)(b<<11) + n)*128 + coff);
    a0 += w * sv.x;
    a1 += w * sv.y;
    a2 += w * sv.z;
    a3 += w * sv.w;
  }
  size_t obase = (size_t)gid*513;
  int c = tid*4;
  float inv = 1.0f / (ipn + 1e-7f);
  out[obase + c+0] = a0*inv;
  out[obase + c+1] = a1*inv;
  out[obase + c+2] = a2*inv;
  out[obase + c+3] = a3*inv;
  if (tid == 0) out[obase + 512] = ipn;
}

extern "C" void kernel_launch(void* const* d_in, const int* in_sizes, int n_in,
                              void* d_out, int out_size, void* d_ws, size_t ws_size,
                              hipStream_t stream){
  const float* ne  = (const float*)d_in[0];
  float* c0  = (float*)d_in[1];   // updated in place (harness restores before every launch)
  float* h0  = (float*)d_in[2];
  float* c1  = (float*)d_in[3];
  float* h1  = (float*)d_in[4];
  const float* ip  = (const float*)d_in[5];
  const float* Wi0 = (const float*)d_in[6];
  const float* Wh0 = (const float*)d_in[7];
  const float* b0  = (const float*)d_in[8];
  const float* Wi1 = (const float*)d_in[9];
  const float* Wh1 = (const float*)d_in[10];
  const float* b1  = (const float*)d_in[11];
  const float* Wr  = (const float*)d_in[12];
  const float* br  = (const float*)d_in[13];
  const float* Wb  = (const float*)d_in[14];
  const float* bb  = (const float*)d_in[15];
  const int* ti  = (const int*)d_in[16];
  const int* fi  = (const int*)d_in[17];
  const int* ri  = (const int*)d_in[18];
  const int* ei  = (const int*)d_in[19];
  const int* rni = (const int*)d_in[20];
  const int* sl  = (const int*)d_in[21];
  const int* cs  = (const int*)d_in[22];
  float* out = (float*)d_out;

  // --- ws layout (total ~2.5 MB) ---
  uint8_t* ws = (uint8_t*)d_ws;
  unsigned short* Bsw0    = (unsigned short*)(ws + 0);         // 262144 B
  unsigned short* Bsw1    = (unsigned short*)(ws + 262144);    // 262144 B
  float*          saved   = (float*)(ws + 524288);             // 131072 B
  float*          wbuf    = (float*)(ws + 655360);             // 786432 B
  int*            counts  = (int*)(ws + 1441792);              // 262144 B
  int*            offsets = (int*)(ws + 1703936);              // 262144 B
  int*            cursor  = (int*)(ws + 1966080);              // 262144 B
  unsigned short* edges   = (unsigned short*)(ws + 2228224);   // 393216 B

  hipMemsetAsync(counts, 0, BN*sizeof(int), stream);
  hipMemsetAsync(cursor, 0, BN*sizeof(int), stream);

  kswz<<<512, 64, 0, stream>>>(Wi0, Wh0, Wi1, Wh1, Bsw0, Bsw1);
  ksave<<<dim3(BB, 2), 512, 0, stream>>>(c0, h0, c1, h1, ei, rni, saved);
  kearly<<<dim3(NN, BB), 128, 0, stream>>>(c0, h0, c1, h1, ip, sl, cs, out);

  // layer 0: A = [ne | h0_old] -> c0,h0 updated in place
  klstm<<<BN/32, 512, 0, stream>>>(ne, h0, Bsw0, b0, c0, h0);
  // layer 1: A = [h0_new | h1_old] -> c1,h1 updated in place
  klstm<<<BN/32, 512, 0, stream>>>(h0, h1, Bsw1, b1, c1, h1);

  krestore<<<dim3(BB, 2), 512, 0, stream>>>(c0, h0, c1, h1, ei, rni, saved);

  kdec<<<BN/4, 256, 0, stream>>>(c0, h0, c1, h1, Wr, br, Wb, bb, ip, ei, rni, wbuf);

  kcount<<<BN/256, 256, 0, stream>>>(ri, ti, fi, counts);
  kscan<<<BB, 256, 0, stream>>>(counts, offsets);
  kfill<<<BN/256, 256, 0, stream>>>(ri, ti, fi, offsets, cursor, edges);

  kagg<<<BN, 128, 0, stream>>>(c0, h0, c1, h1, wbuf, edges, counts, offsets,
                               sl, cs, out);
}